// Round 1
// baseline (286.401 us; speedup 1.0000x reference)
//
#include <hip/hip_runtime.h>

#define CH 256
#define KK 4
#define HW 64
#define PLANE 4096      // 64*64
#define TILE_W 66       // 64 + 2 halo

// ---------------- Kernel 1: global average pool per (b,c) plane ----------------
__global__ void gap_kernel(const float* __restrict__ x, float* __restrict__ g) {
    int plane = blockIdx.x;                       // b*CH + c
    const float4* p = (const float4*)(x + (size_t)plane * PLANE);
    float sum = 0.f;
    for (int i = threadIdx.x; i < PLANE / 4; i += 256) {
        float4 v = p[i];
        sum += (v.x + v.y) + (v.z + v.w);
    }
    // wave64 butterfly-down reduce
    for (int off = 32; off > 0; off >>= 1)
        sum += __shfl_down(sum, off);
    __shared__ float ws[4];
    int lane = threadIdx.x & 63;
    int wid  = threadIdx.x >> 6;
    if (lane == 0) ws[wid] = sum;
    __syncthreads();
    if (threadIdx.x == 0)
        g[plane] = (ws[0] + ws[1] + ws[2] + ws[3]) * (1.f / PLANE);
}

// ---------------- Kernel 2: attention MLP + softmax over K, one block per batch ----------------
__global__ void attn_kernel(const float* __restrict__ g,
                            const float* __restrict__ fc1_w, const float* __restrict__ fc1_b,
                            const float* __restrict__ fc2_w, const float* __restrict__ fc2_b,
                            float* __restrict__ attn) {
    int b = blockIdx.x;
    int t = threadIdx.x;                          // 0..63, one wave
    __shared__ float gs[CH];
    __shared__ float h[64];
    __shared__ float logit[KK];
    for (int i = t; i < CH; i += 64) gs[i] = g[b * CH + i];
    __syncthreads();
    // fc1 (64 x 256) + relu — one output per thread
    float acc = fc1_b[t];
    const float* wrow = fc1_w + t * CH;
    for (int i = 0; i < CH; ++i) acc = fmaf(wrow[i], gs[i], acc);
    h[t] = fmaxf(acc, 0.f);
    __syncthreads();
    // fc2 (4 x 64)
    if (t < KK) {
        float a = fc2_b[t];
        const float* w2 = fc2_w + t * 64;
        for (int i = 0; i < 64; ++i) a = fmaf(w2[i], h[i], a);
        logit[t] = a;
    }
    __syncthreads();
    if (t == 0) {
        float m = fmaxf(fmaxf(logit[0], logit[1]), fmaxf(logit[2], logit[3]));
        float e[KK];
        float s = 0.f;
        for (int k = 0; k < KK; ++k) { e[k] = expf(logit[k] - m); s += e[k]; }
        float inv = 1.f / s;
        for (int k = 0; k < KK; ++k) attn[b * KK + k] = e[k] * inv;
    }
}

// ---------------- Kernel 3: depthwise 3x3 conv with attention-combined weights ----------------
__global__ void dwconv_kernel(const float* __restrict__ x, const float* __restrict__ conv_w,
                              const float* __restrict__ attn, float* __restrict__ out) {
    int plane = blockIdx.x;                       // b*CH + c
    int b = plane >> 8;
    int c = plane & (CH - 1);
    __shared__ float tile[TILE_W * TILE_W];

    const float* xp = x + (size_t)plane * PLANE;
    // stage zero-padded 66x66 tile
    for (int i = threadIdx.x; i < TILE_W * TILE_W; i += 256) {
        int sy = i / TILE_W;
        int sx = i - sy * TILE_W;
        int gy = sy - 1, gx = sx - 1;
        float v = 0.f;
        if ((unsigned)gy < 64u && (unsigned)gx < 64u) v = xp[(gy << 6) + gx];
        tile[i] = v;
    }

    // effective 3x3 kernel = attn-weighted sum of the K kernels (linearity of conv)
    float a0 = attn[b * KK + 0], a1 = attn[b * KK + 1],
          a2 = attn[b * KK + 2], a3 = attn[b * KK + 3];
    float w[9];
    #pragma unroll
    for (int j = 0; j < 9; ++j) {
        w[j] = a0 * conv_w[(0 * CH + c) * 9 + j]
             + a1 * conv_w[(1 * CH + c) * 9 + j]
             + a2 * conv_w[(2 * CH + c) * 9 + j]
             + a3 * conv_w[(3 * CH + c) * 9 + j];
    }
    __syncthreads();

    float* op = out + (size_t)plane * PLANE;
    for (int i = threadIdx.x; i < PLANE; i += 256) {
        int y  = i >> 6;
        int xx = i & 63;
        const float* t0 = &tile[y * TILE_W + xx];   // = input (y-1, xx-1)
        float r = t0[0]            * w[0] + t0[1]            * w[1] + t0[2]            * w[2]
                + t0[TILE_W]       * w[3] + t0[TILE_W + 1]   * w[4] + t0[TILE_W + 2]   * w[5]
                + t0[2 * TILE_W]   * w[6] + t0[2 * TILE_W+1] * w[7] + t0[2 * TILE_W+2] * w[8];
        op[i] = r;
    }
}

extern "C" void kernel_launch(void* const* d_in, const int* in_sizes, int n_in,
                              void* d_out, int out_size, void* d_ws, size_t ws_size,
                              hipStream_t stream) {
    const float* x      = (const float*)d_in[0];
    const float* conv_w = (const float*)d_in[1];
    const float* fc1_w  = (const float*)d_in[2];
    const float* fc1_b  = (const float*)d_in[3];
    const float* fc2_w  = (const float*)d_in[4];
    const float* fc2_b  = (const float*)d_in[5];
    float* out = (float*)d_out;

    int B = in_sizes[0] / (CH * HW * HW);         // 32

    float* g    = (float*)d_ws;                   // B*CH floats
    float* attn = g + B * CH;                     // B*KK floats

    gap_kernel <<<B * CH, 256, 0, stream>>>(x, g);
    attn_kernel<<<B, 64, 0, stream>>>(g, fc1_w, fc1_b, fc2_w, fc2_b, attn);
    dwconv_kernel<<<B * CH, 256, 0, stream>>>(x, conv_w, attn, out);
}

// Round 3
// 262.354 us; speedup vs baseline: 1.0917x; 1.0917x over previous
//
#include <hip/hip_runtime.h>

#define CH 256
#define KK 4
#define HW 64
#define PLANE 4096      // 64*64
#define TS 67           // LDS tile row stride (66 logical cols + 1 pad -> conflict-free banks)

typedef float fx4 __attribute__((ext_vector_type(4)));   // clang-native vec4 (nontemporal-store OK)

// ---------------- Kernel 1: global average pool per (b,c) plane ----------------
__global__ __launch_bounds__(256) void gap_kernel(const float* __restrict__ x,
                                                  float* __restrict__ g) {
    int plane = blockIdx.x;                       // b*CH + c
    const float4* p = (const float4*)(x + (size_t)plane * PLANE);
    float sum = 0.f;
    #pragma unroll
    for (int k = 0; k < 4; ++k) {
        float4 v = p[threadIdx.x + k * 256];
        sum += (v.x + v.y) + (v.z + v.w);
    }
    for (int off = 32; off > 0; off >>= 1)
        sum += __shfl_down(sum, off);
    __shared__ float ws[4];
    int lane = threadIdx.x & 63;
    int wid  = threadIdx.x >> 6;
    if (lane == 0) ws[wid] = sum;
    __syncthreads();
    if (threadIdx.x == 0)
        g[plane] = (ws[0] + ws[1] + ws[2] + ws[3]) * (1.f / PLANE);
}

// ---------------- Kernel 2: attention MLP + softmax over K ----------------
__global__ __launch_bounds__(64) void attn_kernel(const float* __restrict__ g,
                            const float* __restrict__ fc1_w, const float* __restrict__ fc1_b,
                            const float* __restrict__ fc2_w, const float* __restrict__ fc2_b,
                            float* __restrict__ attn) {
    int b = blockIdx.x;
    int t = threadIdx.x;                          // 0..63, one wave
    __shared__ float gs[CH];
    __shared__ float h[64];
    __shared__ float logit[KK];
    for (int i = t; i < CH; i += 64) gs[i] = g[b * CH + i];
    __syncthreads();
    // fc1 (64 x 256) + relu — one output per thread, 4-way split accumulators
    {
        const float4* wr = (const float4*)(fc1_w + t * CH);
        const float4* gv = (const float4*)gs;
        float a0 = fc1_b[t], a1 = 0.f, a2 = 0.f, a3 = 0.f;
        #pragma unroll 4
        for (int i = 0; i < CH / 4; ++i) {
            float4 w4 = wr[i], g4 = gv[i];
            a0 = fmaf(w4.x, g4.x, a0);
            a1 = fmaf(w4.y, g4.y, a1);
            a2 = fmaf(w4.z, g4.z, a2);
            a3 = fmaf(w4.w, g4.w, a3);
        }
        h[t] = fmaxf((a0 + a1) + (a2 + a3), 0.f);
    }
    __syncthreads();
    if (t < KK) {
        const float4* w2 = (const float4*)(fc2_w + t * 64);
        const float4* hv = (const float4*)h;
        float a0 = fc2_b[t], a1 = 0.f, a2 = 0.f, a3 = 0.f;
        #pragma unroll
        for (int i = 0; i < 16; ++i) {
            float4 w4 = w2[i], h4 = hv[i];
            a0 = fmaf(w4.x, h4.x, a0);
            a1 = fmaf(w4.y, h4.y, a1);
            a2 = fmaf(w4.z, h4.z, a2);
            a3 = fmaf(w4.w, h4.w, a3);
        }
        logit[t] = (a0 + a1) + (a2 + a3);
    }
    __syncthreads();
    if (t == 0) {
        float m = fmaxf(fmaxf(logit[0], logit[1]), fmaxf(logit[2], logit[3]));
        float e[KK];
        float s = 0.f;
        #pragma unroll
        for (int k = 0; k < KK; ++k) { e[k] = __expf(logit[k] - m); s += e[k]; }
        float inv = 1.f / s;
        #pragma unroll
        for (int k = 0; k < KK; ++k) attn[b * KK + k] = e[k] * inv;
    }
}

// ---------------- Kernel 3: depthwise 3x3 conv with attention-combined weights ----------------
// tile[r*TS + c] holds input pixel (r-1, c-1); logical tile 66 rows x 66 cols.
__global__ __launch_bounds__(256) void dwconv_kernel(const float* __restrict__ x,
                              const float* __restrict__ conv_w,
                              const float* __restrict__ attn, float* __restrict__ out) {
    int plane = blockIdx.x;                       // b*CH + c
    int b = plane >> 8;
    int c = plane & (CH - 1);
    __shared__ float tile[66 * TS];
    int t = threadIdx.x;

    // ---- zero halo (260 cells): top row, bottom row, left col, right col ----
    for (int i = t; i < 260; i += 256) {
        int idx;
        if (i < 66)       idx = i;                       // top row r=0, c=i
        else if (i < 132) idx = 65 * TS + (i - 66);      // bottom row r=65
        else if (i < 196) idx = (i - 131) * TS;          // left col c=0, r=1..64
        else              idx = (i - 195) * TS + 65;     // right col c=65, r=1..64
        tile[idx] = 0.f;
    }

    // ---- stage interior with coalesced float4 loads ----
    const float4* xp4 = (const float4*)(x + (size_t)plane * PLANE);
    #pragma unroll
    for (int k = 0; k < 4; ++k) {
        int idx = t + k * 256;                    // 0..1023
        int y   = idx >> 4;                       // 0..63
        int xq  = (idx & 15) << 2;                // 0,4,...,60
        float4 v = xp4[idx];
        float* d = &tile[(y + 1) * TS + 1 + xq];
        d[0] = v.x; d[1] = v.y; d[2] = v.z; d[3] = v.w;
    }

    // ---- effective 3x3 kernel = attn-weighted sum of K kernels (linearity) ----
    float a0 = attn[b * KK + 0], a1 = attn[b * KK + 1],
          a2 = attn[b * KK + 2], a3 = attn[b * KK + 3];
    float w[9];
    #pragma unroll
    for (int j = 0; j < 9; ++j) {
        w[j] = a0 * conv_w[(0 * CH + c) * 9 + j]
             + a1 * conv_w[(1 * CH + c) * 9 + j]
             + a2 * conv_w[(2 * CH + c) * 9 + j]
             + a3 * conv_w[(3 * CH + c) * 9 + j];
    }
    __syncthreads();

    // ---- compute: each thread does 4 adjacent pixels x 4 row-groups ----
    int y0 = t >> 4;                              // 0..15
    int xq = (t & 15) << 2;                       // output col of first pixel
    fx4* op4 = (fx4*)(out + (size_t)plane * PLANE);
    #pragma unroll
    for (int gi = 0; gi < 4; ++gi) {
        int y = y0 + gi * 16;
        float s0 = 0.f, s1 = 0.f, s2 = 0.f, s3 = 0.f;
        #pragma unroll
        for (int dy = 0; dy < 3; ++dy) {
            const float* r = &tile[(y + dy) * TS + xq];
            float e0 = r[0], e1 = r[1], e2 = r[2], e3 = r[3], e4 = r[4], e5 = r[5];
            float w0 = w[dy * 3], w1 = w[dy * 3 + 1], w2 = w[dy * 3 + 2];
            s0 = fmaf(e0, w0, fmaf(e1, w1, fmaf(e2, w2, s0)));
            s1 = fmaf(e1, w0, fmaf(e2, w1, fmaf(e3, w2, s1)));
            s2 = fmaf(e2, w0, fmaf(e3, w1, fmaf(e4, w2, s2)));
            s3 = fmaf(e3, w0, fmaf(e4, w1, fmaf(e5, w2, s3)));
        }
        fx4 res = {s0, s1, s2, s3};
        __builtin_nontemporal_store(res, &op4[(y << 4) + (t & 15)]);
    }
}

extern "C" void kernel_launch(void* const* d_in, const int* in_sizes, int n_in,
                              void* d_out, int out_size, void* d_ws, size_t ws_size,
                              hipStream_t stream) {
    const float* x      = (const float*)d_in[0];
    const float* conv_w = (const float*)d_in[1];
    const float* fc1_w  = (const float*)d_in[2];
    const float* fc1_b  = (const float*)d_in[3];
    const float* fc2_w  = (const float*)d_in[4];
    const float* fc2_b  = (const float*)d_in[5];
    float* out = (float*)d_out;

    int B = in_sizes[0] / (CH * HW * HW);         // 32

    float* g    = (float*)d_ws;                   // B*CH floats
    float* attn = g + B * CH;                     // B*KK floats

    gap_kernel <<<B * CH, 256, 0, stream>>>(x, g);
    attn_kernel<<<B, 64, 0, stream>>>(g, fc1_w, fc1_b, fc2_w, fc2_b, attn);
    dwconv_kernel<<<B * CH, 256, 0, stream>>>(x, conv_w, attn, out);
}